// Round 18
// baseline (93.571 us; speedup 1.0000x reference)
//
#include <hip/hip_runtime.h>
#include <hip/hip_bf16.h>

#define NREL 8
#define CH   64   // IN_CH == HID_CH == 64
#define NPB  16   // nodes per block in fused agg+gemm

typedef unsigned int uint32;
typedef __attribute__((ext_vector_type(8))) short bf16x8;
typedef __attribute__((ext_vector_type(4))) float f32x4;
union U4 { uint4 u; bf16x8 v; };

// ---- bf16 helpers (RNE) ----------------------------------------------------
static __device__ __forceinline__ uint32 packbf(float a, float b) {
    uint32 ua = __float_as_uint(a), ub = __float_as_uint(b);
    ua = (ua + 0x7fffu + ((ua >> 16) & 1u)) >> 16;          // low half  (elem 0 = even k)
    ub = (ub + 0x7fffu + ((ub >> 16) & 1u)) & 0xffff0000u;  // high half (elem 1 = odd k)
    return ua | ub;
}
static __device__ __forceinline__ float bflo(uint32 w) { return __uint_as_float(w << 16); }
static __device__ __forceinline__ float bfhi(uint32 w) { return __uint_as_float(w & 0xffff0000u); }

// ---------------------------------------------------------------------------
// prep2: one kernel, three independent roles by block range [r14-verified].
// ---------------------------------------------------------------------------
__global__ __launch_bounds__(256) void prep2_k(
    const float* __restrict__ x, uint32* __restrict__ xbf,
    const float* __restrict__ Wf, uint32* __restrict__ Bfrag,
    const int* __restrict__ ei, int* __restrict__ ccnt,
    int n2, int nE, int nXB)
{
    const int b = blockIdx.x;
    if (b < 16) {
        const int idx  = b * 256 + threadIdx.x;             // 0..4095
        const int lane = idx & 63;
        const int c    = (idx >> 6) & 3;
        const int ks   = idx >> 8;                          // 0..15
        const int col  = c * 16 + (lane & 15);
        const int k0   = ks * 32 + (lane >> 4) * 8;
        uint4 o;
        o.x = packbf(Wf[(k0 + 0) * 64 + col], Wf[(k0 + 1) * 64 + col]);
        o.y = packbf(Wf[(k0 + 2) * 64 + col], Wf[(k0 + 3) * 64 + col]);
        o.z = packbf(Wf[(k0 + 4) * 64 + col], Wf[(k0 + 5) * 64 + col]);
        o.w = packbf(Wf[(k0 + 6) * 64 + col], Wf[(k0 + 7) * 64 + col]);
        *(uint4*)(Bfrag + (size_t)idx * 4) = o;
    } else if (b < 16 + nXB) {
        const int i = (b - 16) * 256 + threadIdx.x;
        if (i < n2) {
            const float2 v = ((const float2*)x)[i];
            xbf[i] = packbf(v.x, v.y);
        }
    } else {
        __shared__ int h[256];
        h[threadIdx.x] = 0;
        __syncthreads();
        const int cb = b - 16 - nXB;                        // 0..255
        for (int e = cb * 256 + threadIdx.x; e < nE; e += 256 * 256)
            atomicAdd(&h[ei[nE + e] >> 8], 1);
        __syncthreads();
        const int c = threadIdx.x;
        if (h[c]) atomicAdd(&ccnt[c], h[c]);
    }
}

// ---------------------------------------------------------------------------
// Coarse binning [r16-verified]: per 4096-edge chunk; cscan folded in via
// shfl wave-scan. Entry pack: (dlow<<24)|(rel<<16)|src.
// ---------------------------------------------------------------------------
__global__ __launch_bounds__(256) void bin_k(
    const int* __restrict__ ei, const int* __restrict__ rel,
    const int* __restrict__ ccnt, int* __restrict__ cur0,
    uint32* __restrict__ binned, int nE)
{
    __shared__ uint32        ent[4096];
    __shared__ unsigned char cid[4096];
    __shared__ int lh[256], lb[256], lc[256], cbl[256], wsum[4];

    const int t = threadIdx.x;

    {
        const int v = ccnt[t];
        int s = v;
        #pragma unroll
        for (int off = 1; off < 64; off <<= 1) {
            const int u = __shfl_up(s, off, 64);
            if ((t & 63) >= off) s += u;
        }
        if ((t & 63) == 63) wsum[t >> 6] = s;
        lh[t] = 0;
        __syncthreads();
        int addv = 0;
        #pragma unroll
        for (int w = 0; w < 3; ++w)
            if (w < (t >> 6)) addv += wsum[w];
        cbl[t] = s - v + addv;      // exclusive prefix
    }
    __syncthreads();

    const int base = blockIdx.x * 4096;
    #pragma unroll
    for (int i = 0; i < 16; ++i) {
        const int idx = t + i * 256;
        const int e   = base + idx;
        if (e < nE) {
            const int dst = ei[nE + e];
            ent[idx] = ((uint32)(dst & 255) << 24) | ((uint32)rel[e] << 16) | (uint32)ei[e];
            const int c = dst >> 8;
            cid[idx] = (unsigned char)c;
            atomicAdd(&lh[c], 1);
        } else {
            cid[idx] = 255;   // sentinel (NC <= 254 guard in launcher)
        }
    }
    __syncthreads();

    if (lh[t]) lb[t] = cbl[t] + atomicAdd(&cur0[t], lh[t]);
    lc[t] = 0;
    __syncthreads();

    #pragma unroll
    for (int i = 0; i < 16; ++i) {
        const int idx = t + i * 256;
        const int c   = cid[idx];
        if (c != 255) {
            const int off = atomicAdd(&lc[c], 1);
            binned[lb[c] + off] = ent[idx];
        }
    }
}

// ---------------------------------------------------------------------------
// Fine sort within one coarse bucket [r16-verified]. shfl-based scans.
// sorted[] keeps (rel<<16)|src.
// ---------------------------------------------------------------------------
__global__ __launch_bounds__(1024) void fsort_k(
    const uint32* __restrict__ binned, const int* __restrict__ ccnt,
    int* __restrict__ start, int* __restrict__ sorted, int NC, int nE)
{
    __shared__ int fh[2048], fex[2048], fcur[2048], ws[16], red[16], nsh[2];
    const int c = blockIdx.x;
    const int t = threadIdx.x;

    {
        int v = (t < c) ? ccnt[t] : 0;
        #pragma unroll
        for (int off = 32; off > 0; off >>= 1) v += __shfl_down(v, off, 64);
        if ((t & 63) == 0) red[t >> 6] = v;
        fh[t] = 0; fh[t + 1024] = 0;
        __syncthreads();
        if (t == 0) {
            int s = 0;
            #pragma unroll
            for (int i = 0; i < 16; ++i) s += red[i];
            nsh[0] = s;
            nsh[1] = s + ccnt[c];
        }
    }
    __syncthreads();
    const int n0 = nsh[0];
    const int n1 = nsh[1];

    for (int j = n0 + t; j < n1; j += 1024) {
        const uint32 en = binned[j];
        atomicAdd(&fh[((en >> 24) << 3) | ((en >> 16) & 7)], 1);
    }
    __syncthreads();

    const int a = fh[2 * t], b = fh[2 * t + 1];
    const int p = a + b;
    int s = p;
    #pragma unroll
    for (int off = 1; off < 64; off <<= 1) {
        const int u = __shfl_up(s, off, 64);
        if ((t & 63) >= off) s += u;
    }
    if ((t & 63) == 63) ws[t >> 6] = s;
    __syncthreads();
    if (t < 16) {
        const int vv = ws[t];
        int ss = vv;
        #pragma unroll
        for (int off = 1; off < 16; off <<= 1) {
            const int u = __shfl_up(ss, off, 16);
            if (t >= off) ss += u;
        }
        ws[t] = ss - vv;            // exclusive wave offset
    }
    __syncthreads();
    const int ep = s - p + ws[t >> 6];
    fex[2 * t] = ep; fex[2 * t + 1] = ep + a;
    __syncthreads();

    fcur[t] = fex[t]; fcur[t + 1024] = fex[t + 1024];
    {
        const int k0 = c << 11;
        start[k0 + t]        = n0 + fex[t];
        start[k0 + t + 1024] = n0 + fex[t + 1024];
    }
    if (c == NC - 1 && t == 0) start[NC << 11] = n1;
    __syncthreads();

    for (int j = n0 + t; j < n1; j += 1024) {
        const uint32 en = binned[j];
        const int fk  = ((en >> 24) << 3) | ((en >> 16) & 7);
        const int off = atomicAdd(&fcur[fk], 1);
        sorted[n0 + off] = (int)(en & 0x7FFFFu);   // (rel<<16)|src
    }
}

// ---------------------------------------------------------------------------
// Fused aggregate + GEMM v4: ONE NODE PER FULL WAVE (was per half-wave).
// Block = 1024 threads = 16 waves = 16 nodes. Each pair-step processes two
// edges: lanes 0-31 gather edge j's xbf row, lanes 32-63 edge j+1's. All
// rel bookkeeping is wave-uniform (codes broadcast by shfl). Flush combines
// the halves via shfl_xor(32); half 0 writes the LDS A-fragment. 4-deep
// pair prefetch keeps 4 gathers in flight. Phase 2 (threads 0-255) MFMA
// col-tiles unchanged. C/D layout per m89: col=lane&15, row=(lane>>4)*4+reg.
// ---------------------------------------------------------------------------
#define PAIR_FLUSH(rr)                                                       \
    {                                                                        \
        const float c0 = a0 + __shfl_xor(a0, 32, 64);                        \
        const float c1 = a1 + __shfl_xor(a1, 32, 64);                        \
        if (!half) {                                                         \
            const int widx = (row * 256 + ((rr) * 2 + (l32 >> 4)) * 16 +     \
                              (l32 & 15)) ^ ((row & 7) << 2);                \
            als[widx] = packbf(c0, c1);                                      \
        }                                                                    \
    }

#define PAIR_STEP(elo, ehi, uu)                                              \
    {                                                                        \
        const int rlo = (int)((elo) >> 16);                                  \
        const int rhi = (int)((ehi) >> 16);                                  \
        if (rlo != prev) {                                                   \
            if (prev >= 0) PAIR_FLUSH(prev);                                 \
            a0 = 0.f; a1 = 0.f;                                              \
            prev = rlo;                                                      \
        }                                                                    \
        if (rhi == rlo) {                                                    \
            a0 += bflo(uu); a1 += bfhi(uu);                                  \
        } else {                                                             \
            if (!half) { a0 += bflo(uu); a1 += bfhi(uu); }                   \
            PAIR_FLUSH(rlo);                                                 \
            a0 = 0.f; a1 = 0.f;                                              \
            prev = rhi;                                                      \
            if (half) { a0 += bflo(uu); a1 += bfhi(uu); }                    \
        }                                                                    \
    }

__global__ __launch_bounds__(1024) void aggemm_k(
    const uint32* __restrict__ xbf, const int* __restrict__ start,
    const int* __restrict__ sorted, const uint32* __restrict__ Bfrag,
    float* __restrict__ out, int nN)
{
    __shared__ uint32 als[NPB * 256];   // 16 KB

    const int t      = threadIdx.x;
    const int row    = t >> 6;          // wave 0..15 = node row
    const int lane   = t & 63;
    const int l32    = t & 31;
    const int half   = (t >> 5) & 1;
    const int n_base = blockIdx.x * NPB;
    const int n      = n_base + row;

    // ---- phase 1: aggregation (one node per wave) ----
    #pragma unroll
    for (int z = 0; z < 4; ++z)
        als[(row * 256 + z * 64 + lane) ^ ((row & 7) << 2)] = 0u;

    if (n < nN) {
        const int kb = n * NREL;
        const int b0 = start[kb];
        const int b8 = start[kb + 8];

        int   prev = -1;
        float a0 = 0.f, a1 = 0.f;

        for (int base = b0; base < b8; base += 64) {
            const int cnt = min(64, b8 - base);
            const int jj  = base + lane;
            const uint32 ev = (jj < b8) ? (uint32)sorted[jj] : 0u;

            int j = 0;
            for (; j + 8 <= cnt; j += 8) {
                const uint32 eA = __shfl(ev, j + 0, 64), eB = __shfl(ev, j + 1, 64);
                const uint32 eC = __shfl(ev, j + 2, 64), eD = __shfl(ev, j + 3, 64);
                const uint32 eE = __shfl(ev, j + 4, 64), eF = __shfl(ev, j + 5, 64);
                const uint32 eG = __shfl(ev, j + 6, 64), eH = __shfl(ev, j + 7, 64);
                const uint32 u0 = xbf[(size_t)((half ? eB : eA) & 0xFFFFu) * 32 + l32];
                const uint32 u1 = xbf[(size_t)((half ? eD : eC) & 0xFFFFu) * 32 + l32];
                const uint32 u2 = xbf[(size_t)((half ? eF : eE) & 0xFFFFu) * 32 + l32];
                const uint32 u3 = xbf[(size_t)((half ? eH : eG) & 0xFFFFu) * 32 + l32];
                PAIR_STEP(eA, eB, u0);
                PAIR_STEP(eC, eD, u1);
                PAIR_STEP(eE, eF, u2);
                PAIR_STEP(eG, eH, u3);
            }
            for (; j + 2 <= cnt; j += 2) {
                const uint32 eA = __shfl(ev, j, 64), eB = __shfl(ev, j + 1, 64);
                const uint32 u0 = xbf[(size_t)((half ? eB : eA) & 0xFFFFu) * 32 + l32];
                PAIR_STEP(eA, eB, u0);
            }
            if (j < cnt) {   // odd tail: single edge, added once (half 0)
                const uint32 e = __shfl(ev, j, 64);
                const uint32 u = xbf[(size_t)(e & 0xFFFFu) * 32 + l32];
                const int r_ = (int)(e >> 16);
                if (r_ != prev) {
                    if (prev >= 0) PAIR_FLUSH(prev);
                    a0 = 0.f; a1 = 0.f;
                    prev = r_;
                }
                if (!half) { a0 += bflo(u); a1 += bfhi(u); }
            }
        }
        if (prev >= 0) PAIR_FLUSH(prev);
    }
    __syncthreads();

    // ---- phase 2: MFMA (threads 0-255 = waves 0-3) ----
    if (t < 256) {
        const int ln = t & 63;
        const int w  = t >> 6;              // col tile 0..3
        const int rl = ln & 15;
        const int kq = ln >> 4;

        f32x4 acc = (f32x4){0.f, 0.f, 0.f, 0.f};
        const uint32* bp = Bfrag + (size_t)ln * 4;

        #pragma unroll
        for (int ks = 0; ks < 16; ++ks) {
            const int aidx = (rl * 256 + ks * 16 + kq * 4) ^ ((rl & 7) << 2);
            U4 ua, ub;
            ua.u = *(const uint4*)(als + aidx);
            ub.u = *(const uint4*)(bp + (size_t)(ks * 4 + w) * 256);
            acc = __builtin_amdgcn_mfma_f32_16x16x32_bf16(ua.v, ub.v, acc, 0, 0, 0);
        }

        #pragma unroll
        for (int reg = 0; reg < 4; ++reg) {
            const int rr = kq * 4 + reg;
            const int nn = n_base + rr;
            if (nn < nN)
                out[(size_t)nn * 64 + w * 16 + rl] = acc[reg];
        }
    }
}

// ---------------------------------------------------------------------------
// Fallback: per-edge direct with atomics.
// ---------------------------------------------------------------------------
__global__ __launch_bounds__(256) void rgcn_direct_kernel(
    const float* __restrict__ x, const float* __restrict__ W,
    const int* __restrict__ ei, const int* __restrict__ rel,
    float* __restrict__ out, int nE, int nWaves)
{
    const int w    = (int)((blockIdx.x * 256u + threadIdx.x) >> 6);
    const int lane = threadIdx.x & 63;

    for (int e = w; e < nE; e += nWaves) {
        const int src = ei[e];
        const int dst = ei[nE + e];
        const int r   = rel[e];
        const float* xrow = x + (size_t)src * CH;
        const float* wcol = W + ((size_t)r << 12) + lane;
        float acc = 0.f;
        #pragma unroll
        for (int i = 0; i < CH; ++i) acc += xrow[i] * wcol[i * CH];
        atomicAdd(out + (size_t)dst * CH + lane, acc);
    }
}

static inline size_t align256(size_t v) { return (v + 255) & ~(size_t)255; }

extern "C" void kernel_launch(void* const* d_in, const int* in_sizes, int n_in,
                              void* d_out, int out_size, void* d_ws, size_t ws_size,
                              hipStream_t stream) {
    const float* x   = (const float*)d_in[0];
    const float* W   = (const float*)d_in[1];
    const int*   ei  = (const int*)d_in[2];
    const int*   rel = (const int*)d_in[3];
    float*       out = (float*)d_out;

    const int nN = in_sizes[0] / CH;   // 50000
    const int nE = in_sizes[3];        // 1000000
    const int NC = (nN + 255) >> 8;    // 196 coarse buckets

    // Workspace layout
    const size_t sz_xbf    = align256((size_t)nN * 32 * sizeof(uint32));        // 6.4 MB
    const size_t sz_start  = align256(((size_t)NC * 2048 + 2) * sizeof(int));   // 1.6 MB
    const size_t sz_binned = align256((size_t)nE * sizeof(uint32));             // 4 MB
    const size_t sz_sorted = align256((size_t)nE * sizeof(int));                // 4 MB
    const size_t sz_bfrag  = align256((size_t)16384 * sizeof(uint32));          // 64 KB
    const size_t sz_ccnt   = align256(256 * sizeof(int));
    const size_t sz_cur0   = align256(256 * sizeof(int));
    const size_t need = sz_xbf + sz_start + sz_binned + sz_sorted +
                        sz_bfrag + sz_ccnt + sz_cur0;

    if (ws_size >= need && nN <= 65024 && NC <= 254) {
        char* p = (char*)d_ws;
        uint32* xbf    = (uint32*)p;  p += sz_xbf;
        int*    start  = (int*)p;     p += sz_start;
        uint32* binned = (uint32*)p;  p += sz_binned;
        int*    sorted = (int*)p;     p += sz_sorted;
        uint32* Bfrag  = (uint32*)p;  p += sz_bfrag;
        int*    ccnt   = (int*)p;     p += sz_ccnt;
        int*    cur0   = (int*)p;

        // one memset covers ccnt + cur0 (contiguous)
        hipMemsetAsync(ccnt, 0, sz_ccnt + sz_cur0, stream);

        const int n2  = nN * 32;
        const int nXB = (n2 + 255) / 256;
        prep2_k<<<16 + nXB + 256, 256, 0, stream>>>(
            x, xbf, W, Bfrag, ei, ccnt, n2, nE, nXB);

        bin_k<<<(nE + 4095) / 4096, 256, 0, stream>>>(ei, rel, ccnt, cur0, binned, nE);
        fsort_k<<<NC, 1024, 0, stream>>>(binned, ccnt, start, sorted, NC, nE);

        aggemm_k<<<(nN + NPB - 1) / NPB, 1024, 0, stream>>>(
            xbf, start, sorted, Bfrag, out, nN);
    } else {
        hipMemsetAsync(out, 0, (size_t)out_size * sizeof(float), stream);
        const int blocks = 2048;
        const int nWaves = blocks * (256 / 64);
        rgcn_direct_kernel<<<blocks, 256, 0, stream>>>(x, W, ei, rel, out, nE, nWaves);
    }
}

// Round 19
// 80.216 us; speedup vs baseline: 1.1665x; 1.1665x over previous
//
#include <hip/hip_runtime.h>
#include <hip/hip_bf16.h>

#define NREL 8
#define CH   64   // IN_CH == HID_CH == 64
#define NPB  16   // nodes per block in fused agg+gemm

typedef unsigned int uint32;
typedef __attribute__((ext_vector_type(8))) short bf16x8;
typedef __attribute__((ext_vector_type(4))) float f32x4;
union U4 { uint4 u; bf16x8 v; };

// ---- bf16 helpers (RNE) ----------------------------------------------------
static __device__ __forceinline__ uint32 packbf(float a, float b) {
    uint32 ua = __float_as_uint(a), ub = __float_as_uint(b);
    ua = (ua + 0x7fffu + ((ua >> 16) & 1u)) >> 16;          // low half  (elem 0 = even k)
    ub = (ub + 0x7fffu + ((ub >> 16) & 1u)) & 0xffff0000u;  // high half (elem 1 = odd k)
    return ua | ub;
}
static __device__ __forceinline__ float bflo(uint32 w) { return __uint_as_float(w << 16); }
static __device__ __forceinline__ float bfhi(uint32 w) { return __uint_as_float(w & 0xffff0000u); }

// ---------------------------------------------------------------------------
// prep2: one kernel, three independent roles by block range [r14-verified].
// ---------------------------------------------------------------------------
__global__ __launch_bounds__(256) void prep2_k(
    const float* __restrict__ x, uint32* __restrict__ xbf,
    const float* __restrict__ Wf, uint32* __restrict__ Bfrag,
    const int* __restrict__ ei, int* __restrict__ ccnt,
    int n2, int nE, int nXB)
{
    const int b = blockIdx.x;
    if (b < 16) {
        const int idx  = b * 256 + threadIdx.x;             // 0..4095
        const int lane = idx & 63;
        const int c    = (idx >> 6) & 3;
        const int ks   = idx >> 8;                          // 0..15
        const int col  = c * 16 + (lane & 15);
        const int k0   = ks * 32 + (lane >> 4) * 8;
        uint4 o;
        o.x = packbf(Wf[(k0 + 0) * 64 + col], Wf[(k0 + 1) * 64 + col]);
        o.y = packbf(Wf[(k0 + 2) * 64 + col], Wf[(k0 + 3) * 64 + col]);
        o.z = packbf(Wf[(k0 + 4) * 64 + col], Wf[(k0 + 5) * 64 + col]);
        o.w = packbf(Wf[(k0 + 6) * 64 + col], Wf[(k0 + 7) * 64 + col]);
        *(uint4*)(Bfrag + (size_t)idx * 4) = o;
    } else if (b < 16 + nXB) {
        const int i = (b - 16) * 256 + threadIdx.x;
        if (i < n2) {
            const float2 v = ((const float2*)x)[i];
            xbf[i] = packbf(v.x, v.y);
        }
    } else {
        __shared__ int h[256];
        h[threadIdx.x] = 0;
        __syncthreads();
        const int cb = b - 16 - nXB;                        // 0..255
        for (int e = cb * 256 + threadIdx.x; e < nE; e += 256 * 256)
            atomicAdd(&h[ei[nE + e] >> 8], 1);
        __syncthreads();
        const int c = threadIdx.x;
        if (h[c]) atomicAdd(&ccnt[c], h[c]);
    }
}

// ---------------------------------------------------------------------------
// Coarse binning [r16-verified]: per 4096-edge chunk; cscan folded in via
// shfl wave-scan. Entry pack: (dlow<<24)|(rel<<16)|src.
// ---------------------------------------------------------------------------
__global__ __launch_bounds__(256) void bin_k(
    const int* __restrict__ ei, const int* __restrict__ rel,
    const int* __restrict__ ccnt, int* __restrict__ cur0,
    uint32* __restrict__ binned, int nE)
{
    __shared__ uint32        ent[4096];
    __shared__ unsigned char cid[4096];
    __shared__ int lh[256], lb[256], lc[256], cbl[256], wsum[4];

    const int t = threadIdx.x;

    {
        const int v = ccnt[t];
        int s = v;
        #pragma unroll
        for (int off = 1; off < 64; off <<= 1) {
            const int u = __shfl_up(s, off, 64);
            if ((t & 63) >= off) s += u;
        }
        if ((t & 63) == 63) wsum[t >> 6] = s;
        lh[t] = 0;
        __syncthreads();
        int addv = 0;
        #pragma unroll
        for (int w = 0; w < 3; ++w)
            if (w < (t >> 6)) addv += wsum[w];
        cbl[t] = s - v + addv;      // exclusive prefix
    }
    __syncthreads();

    const int base = blockIdx.x * 4096;
    #pragma unroll
    for (int i = 0; i < 16; ++i) {
        const int idx = t + i * 256;
        const int e   = base + idx;
        if (e < nE) {
            const int dst = ei[nE + e];
            ent[idx] = ((uint32)(dst & 255) << 24) | ((uint32)rel[e] << 16) | (uint32)ei[e];
            const int c = dst >> 8;
            cid[idx] = (unsigned char)c;
            atomicAdd(&lh[c], 1);
        } else {
            cid[idx] = 255;   // sentinel (NC <= 254 guard in launcher)
        }
    }
    __syncthreads();

    if (lh[t]) lb[t] = cbl[t] + atomicAdd(&cur0[t], lh[t]);
    lc[t] = 0;
    __syncthreads();

    #pragma unroll
    for (int i = 0; i < 16; ++i) {
        const int idx = t + i * 256;
        const int c   = cid[idx];
        if (c != 255) {
            const int off = atomicAdd(&lc[c], 1);
            binned[lb[c] + off] = ent[idx];
        }
    }
}

// ---------------------------------------------------------------------------
// Fine sort within one coarse bucket [r16-verified]. shfl-based scans.
// sorted[] keeps (rel<<16)|src.
// ---------------------------------------------------------------------------
__global__ __launch_bounds__(1024) void fsort_k(
    const uint32* __restrict__ binned, const int* __restrict__ ccnt,
    int* __restrict__ start, int* __restrict__ sorted, int NC, int nE)
{
    __shared__ int fh[2048], fex[2048], fcur[2048], ws[16], red[16], nsh[2];
    const int c = blockIdx.x;
    const int t = threadIdx.x;

    {
        int v = (t < c) ? ccnt[t] : 0;
        #pragma unroll
        for (int off = 32; off > 0; off >>= 1) v += __shfl_down(v, off, 64);
        if ((t & 63) == 0) red[t >> 6] = v;
        fh[t] = 0; fh[t + 1024] = 0;
        __syncthreads();
        if (t == 0) {
            int s = 0;
            #pragma unroll
            for (int i = 0; i < 16; ++i) s += red[i];
            nsh[0] = s;
            nsh[1] = s + ccnt[c];
        }
    }
    __syncthreads();
    const int n0 = nsh[0];
    const int n1 = nsh[1];

    for (int j = n0 + t; j < n1; j += 1024) {
        const uint32 en = binned[j];
        atomicAdd(&fh[((en >> 24) << 3) | ((en >> 16) & 7)], 1);
    }
    __syncthreads();

    const int a = fh[2 * t], b = fh[2 * t + 1];
    const int p = a + b;
    int s = p;
    #pragma unroll
    for (int off = 1; off < 64; off <<= 1) {
        const int u = __shfl_up(s, off, 64);
        if ((t & 63) >= off) s += u;
    }
    if ((t & 63) == 63) ws[t >> 6] = s;
    __syncthreads();
    if (t < 16) {
        const int vv = ws[t];
        int ss = vv;
        #pragma unroll
        for (int off = 1; off < 16; off <<= 1) {
            const int u = __shfl_up(ss, off, 16);
            if (t >= off) ss += u;
        }
        ws[t] = ss - vv;            // exclusive wave offset
    }
    __syncthreads();
    const int ep = s - p + ws[t >> 6];
    fex[2 * t] = ep; fex[2 * t + 1] = ep + a;
    __syncthreads();

    fcur[t] = fex[t]; fcur[t + 1024] = fex[t + 1024];
    {
        const int k0 = c << 11;
        start[k0 + t]        = n0 + fex[t];
        start[k0 + t + 1024] = n0 + fex[t + 1024];
    }
    if (c == NC - 1 && t == 0) start[NC << 11] = n1;
    __syncthreads();

    for (int j = n0 + t; j < n1; j += 1024) {
        const uint32 en = binned[j];
        const int fk  = ((en >> 24) << 3) | ((en >> 16) & 7);
        const int off = atomicAdd(&fcur[fk], 1);
        sorted[n0 + off] = (int)(en & 0x7FFFFu);   // (rel<<16)|src
    }
}

// ---------------------------------------------------------------------------
// Fused aggregate + GEMM [r15/r17-verified, best known]. Block = 512 threads
// = 16 half-waves, ONE node per half-wave. Edge codes per 32-chunk loaded
// once coalesced and broadcast via __shfl; flush-on-rel-change into
// XOR-swizzled LDS A-tile; one barrier; waves 0-3 run the 16-step MFMA
// col-tiles. C/D layout per m89: col=lane&15, row=(lane>>4)*4+reg.
// ---------------------------------------------------------------------------
#define AGG_FLUSH()                                                          \
    {                                                                        \
        const int widx = (row * 256 + (prev * 2 + (l32 >> 4)) * 16 +         \
                          (l32 & 15)) ^ ((row & 7) << 2);                    \
        als[widx] = packbf(a0, a1);                                          \
    }

#define AGG_PROCESS(eu, uu)                                                  \
    {                                                                        \
        const int r_ = (int)((eu) >> 16);                                    \
        if (r_ != prev) {                                                    \
            if (prev >= 0) AGG_FLUSH();                                      \
            a0 = 0.f; a1 = 0.f;                                              \
            prev = r_;                                                       \
        }                                                                    \
        a0 += bflo(uu); a1 += bfhi(uu);                                      \
    }

__global__ __launch_bounds__(512) void aggemm_k(
    const uint32* __restrict__ xbf, const int* __restrict__ start,
    const int* __restrict__ sorted, const uint32* __restrict__ Bfrag,
    float* __restrict__ out, int nN)
{
    __shared__ uint32 als[NPB * 256];   // 16 KB

    const int t      = threadIdx.x;
    const int row    = t >> 5;          // half-wave 0..15 = node row
    const int l32    = t & 31;
    const int n_base = blockIdx.x * NPB;
    const int n      = n_base + row;

    // ---- phase 1: aggregation (one node per half-wave) ----
    #pragma unroll
    for (int z = 0; z < 8; ++z)
        als[(row * 256 + z * 32 + l32) ^ ((row & 7) << 2)] = 0u;

    if (n < nN) {
        const int kb = n * NREL;
        const int b0 = start[kb];
        const int b8 = start[kb + 8];

        int   prev = -1;
        float a0 = 0.f, a1 = 0.f;

        for (int base = b0; base < b8; base += 32) {
            const int cnt = min(32, b8 - base);
            const int jj  = base + l32;
            const uint32 ev = (jj < b8) ? (uint32)sorted[jj] : 0u;

            int j = 0;
            for (; j + 8 <= cnt; j += 8) {
                const uint32 e0 = __shfl(ev, j + 0, 32);
                const uint32 e1 = __shfl(ev, j + 1, 32);
                const uint32 e2 = __shfl(ev, j + 2, 32);
                const uint32 e3 = __shfl(ev, j + 3, 32);
                const uint32 e4 = __shfl(ev, j + 4, 32);
                const uint32 e5 = __shfl(ev, j + 5, 32);
                const uint32 e6 = __shfl(ev, j + 6, 32);
                const uint32 e7 = __shfl(ev, j + 7, 32);
                const uint32 u0 = xbf[(size_t)(e0 & 0xFFFFu) * 32 + l32];
                const uint32 u1 = xbf[(size_t)(e1 & 0xFFFFu) * 32 + l32];
                const uint32 u2 = xbf[(size_t)(e2 & 0xFFFFu) * 32 + l32];
                const uint32 u3 = xbf[(size_t)(e3 & 0xFFFFu) * 32 + l32];
                const uint32 u4 = xbf[(size_t)(e4 & 0xFFFFu) * 32 + l32];
                const uint32 u5 = xbf[(size_t)(e5 & 0xFFFFu) * 32 + l32];
                const uint32 u6 = xbf[(size_t)(e6 & 0xFFFFu) * 32 + l32];
                const uint32 u7 = xbf[(size_t)(e7 & 0xFFFFu) * 32 + l32];
                AGG_PROCESS(e0, u0);
                AGG_PROCESS(e1, u1);
                AGG_PROCESS(e2, u2);
                AGG_PROCESS(e3, u3);
                AGG_PROCESS(e4, u4);
                AGG_PROCESS(e5, u5);
                AGG_PROCESS(e6, u6);
                AGG_PROCESS(e7, u7);
            }
            for (; j + 4 <= cnt; j += 4) {
                const uint32 e0 = __shfl(ev, j + 0, 32);
                const uint32 e1 = __shfl(ev, j + 1, 32);
                const uint32 e2 = __shfl(ev, j + 2, 32);
                const uint32 e3 = __shfl(ev, j + 3, 32);
                const uint32 u0 = xbf[(size_t)(e0 & 0xFFFFu) * 32 + l32];
                const uint32 u1 = xbf[(size_t)(e1 & 0xFFFFu) * 32 + l32];
                const uint32 u2 = xbf[(size_t)(e2 & 0xFFFFu) * 32 + l32];
                const uint32 u3 = xbf[(size_t)(e3 & 0xFFFFu) * 32 + l32];
                AGG_PROCESS(e0, u0);
                AGG_PROCESS(e1, u1);
                AGG_PROCESS(e2, u2);
                AGG_PROCESS(e3, u3);
            }
            for (; j < cnt; ++j) {
                const uint32 e = __shfl(ev, j, 32);
                const uint32 u = xbf[(size_t)(e & 0xFFFFu) * 32 + l32];
                AGG_PROCESS(e, u);
            }
        }
        if (prev >= 0) AGG_FLUSH();
    }
    __syncthreads();

    // ---- phase 2: MFMA (waves 0-3 only) ----
    if (t < 256) {
        const int lane = t & 63;
        const int w    = t >> 6;            // col tile 0..3
        const int rl   = lane & 15;
        const int kq   = lane >> 4;

        f32x4 acc = (f32x4){0.f, 0.f, 0.f, 0.f};
        const uint32* bp = Bfrag + (size_t)lane * 4;

        #pragma unroll
        for (int ks = 0; ks < 16; ++ks) {
            const int aidx = (rl * 256 + ks * 16 + kq * 4) ^ ((rl & 7) << 2);
            U4 ua, ub;
            ua.u = *(const uint4*)(als + aidx);
            ub.u = *(const uint4*)(bp + (size_t)(ks * 4 + w) * 256);
            acc = __builtin_amdgcn_mfma_f32_16x16x32_bf16(ua.v, ub.v, acc, 0, 0, 0);
        }

        #pragma unroll
        for (int reg = 0; reg < 4; ++reg) {
            const int rr = kq * 4 + reg;
            const int nn = n_base + rr;
            if (nn < nN)
                out[(size_t)nn * 64 + w * 16 + rl] = acc[reg];
        }
    }
}

// ---------------------------------------------------------------------------
// Fallback: per-edge direct with atomics.
// ---------------------------------------------------------------------------
__global__ __launch_bounds__(256) void rgcn_direct_kernel(
    const float* __restrict__ x, const float* __restrict__ W,
    const int* __restrict__ ei, const int* __restrict__ rel,
    float* __restrict__ out, int nE, int nWaves)
{
    const int w    = (int)((blockIdx.x * 256u + threadIdx.x) >> 6);
    const int lane = threadIdx.x & 63;

    for (int e = w; e < nE; e += nWaves) {
        const int src = ei[e];
        const int dst = ei[nE + e];
        const int r   = rel[e];
        const float* xrow = x + (size_t)src * CH;
        const float* wcol = W + ((size_t)r << 12) + lane;
        float acc = 0.f;
        #pragma unroll
        for (int i = 0; i < CH; ++i) acc += xrow[i] * wcol[i * CH];
        atomicAdd(out + (size_t)dst * CH + lane, acc);
    }
}

static inline size_t align256(size_t v) { return (v + 255) & ~(size_t)255; }

extern "C" void kernel_launch(void* const* d_in, const int* in_sizes, int n_in,
                              void* d_out, int out_size, void* d_ws, size_t ws_size,
                              hipStream_t stream) {
    const float* x   = (const float*)d_in[0];
    const float* W   = (const float*)d_in[1];
    const int*   ei  = (const int*)d_in[2];
    const int*   rel = (const int*)d_in[3];
    float*       out = (float*)d_out;

    const int nN = in_sizes[0] / CH;   // 50000
    const int nE = in_sizes[3];        // 1000000
    const int NC = (nN + 255) >> 8;    // 196 coarse buckets

    // Workspace layout
    const size_t sz_xbf    = align256((size_t)nN * 32 * sizeof(uint32));        // 6.4 MB
    const size_t sz_start  = align256(((size_t)NC * 2048 + 2) * sizeof(int));   // 1.6 MB
    const size_t sz_binned = align256((size_t)nE * sizeof(uint32));             // 4 MB
    const size_t sz_sorted = align256((size_t)nE * sizeof(int));                // 4 MB
    const size_t sz_bfrag  = align256((size_t)16384 * sizeof(uint32));          // 64 KB
    const size_t sz_ccnt   = align256(256 * sizeof(int));
    const size_t sz_cur0   = align256(256 * sizeof(int));
    const size_t need = sz_xbf + sz_start + sz_binned + sz_sorted +
                        sz_bfrag + sz_ccnt + sz_cur0;

    if (ws_size >= need && nN <= 65024 && NC <= 254) {
        char* p = (char*)d_ws;
        uint32* xbf    = (uint32*)p;  p += sz_xbf;
        int*    start  = (int*)p;     p += sz_start;
        uint32* binned = (uint32*)p;  p += sz_binned;
        int*    sorted = (int*)p;     p += sz_sorted;
        uint32* Bfrag  = (uint32*)p;  p += sz_bfrag;
        int*    ccnt   = (int*)p;     p += sz_ccnt;
        int*    cur0   = (int*)p;

        // one memset covers ccnt + cur0 (contiguous)
        hipMemsetAsync(ccnt, 0, sz_ccnt + sz_cur0, stream);

        const int n2  = nN * 32;
        const int nXB = (n2 + 255) / 256;
        prep2_k<<<16 + nXB + 256, 256, 0, stream>>>(
            x, xbf, W, Bfrag, ei, ccnt, n2, nE, nXB);

        bin_k<<<(nE + 4095) / 4096, 256, 0, stream>>>(ei, rel, ccnt, cur0, binned, nE);
        fsort_k<<<NC, 1024, 0, stream>>>(binned, ccnt, start, sorted, NC, nE);

        aggemm_k<<<(nN + NPB - 1) / NPB, 512, 0, stream>>>(
            xbf, start, sorted, Bfrag, out, nN);
    } else {
        hipMemsetAsync(out, 0, (size_t)out_size * sizeof(float), stream);
        const int blocks = 2048;
        const int nWaves = blocks * (256 / 64);
        rgcn_direct_kernel<<<blocks, 256, 0, stream>>>(x, W, ei, rel, out, nE, nWaves);
    }
}